// Round 4
// baseline (330.789 us; speedup 1.0000x reference)
//
#include <hip/hip_runtime.h>
#include <hip/hip_bf16.h>
#include <stdint.h>

// Problem constants
#define BATCH 64
#define IN_CAPS 512          // In (input capsules)
#define NCAP 16              // num_capsule
#define DCAP 64              // dim_capsule
#define GN (NCAP * DCAP)     // 1024
#define GM (BATCH * IN_CAPS) // 32768
#define GK 768               // input feature dim (K)

typedef __bf16 bf16;
typedef __attribute__((ext_vector_type(8))) __bf16 bf16x8;
typedef __attribute__((ext_vector_type(4))) float f32x4;

// async global->LDS 16B copy (wave-uniform LDS base + lane*16)
__device__ inline void async16(const bf16* g, bf16* l) {
    __builtin_amdgcn_global_load_lds(
        (__attribute__((address_space(1))) void*)g,
        (__attribute__((address_space(3))) void*)l, 16, 0, 0);
}

// ---------------------------------------------------------------------------
// Kernel 1: X (fp32) -> bf16 convert + per-b row-sum partials (for out1).
// Register accumulation (round-3 validated), single LDS merge at the end.
// ---------------------------------------------------------------------------
__global__ __launch_bounds__(256) void k_convX2(const float* __restrict__ X,
                                                bf16* __restrict__ Xb,
                                                float* __restrict__ XS) {
    __shared__ float ls[GK];
    const int tid = threadIdx.x;
    ls[tid] = 0.f; ls[tid + 256] = 0.f; ls[tid + 512] = 0.f;
    __syncthreads();
    const size_t base = (size_t)blockIdx.x * (32 * GK);
    float acc[3][8] = {};  // static indices only (g = r%3 is compile-time)
#pragma unroll
    for (int r = 0; r < 12; ++r) {
        const int off = r * 2048 + tid * 8;  // 12*2048 = 24576 = 32*768
        const f32x4 a0 = *(const f32x4*)(X + base + off);
        const f32x4 a1 = *(const f32x4*)(X + base + off + 4);
        bf16x8 o;
        o[0] = (bf16)a0[0]; o[1] = (bf16)a0[1]; o[2] = (bf16)a0[2]; o[3] = (bf16)a0[3];
        o[4] = (bf16)a1[0]; o[5] = (bf16)a1[1]; o[6] = (bf16)a1[2]; o[7] = (bf16)a1[3];
        *(bf16x8*)(Xb + base + off) = o;
        const int g = r % 3;  // compile-time within the unrolled body
        acc[g][0] += a0[0]; acc[g][1] += a0[1];
        acc[g][2] += a0[2]; acc[g][3] += a0[3];
        acc[g][4] += a1[0]; acc[g][5] += a1[1];
        acc[g][6] += a1[2]; acc[g][7] += a1[3];
    }
    if (XS != nullptr) {
        // one-time merge: 24 LDS atomics/thread, off the streaming path
#pragma unroll
        for (int g = 0; g < 3; ++g) {
            const int cg = (g == 1) ? 512 : (g == 2) ? 256 : 0;
            const int kb = (tid * 8 + cg) % GK;  // 8-group never straddles row end
#pragma unroll
            for (int j = 0; j < 8; ++j) atomicAdd(&ls[kb + j], acc[g][j]);
        }
        __syncthreads();
        const int bidx = blockIdx.x >> 4;  // 16 blocks of 32 rows per b
        atomicAdd(&XS[(size_t)bidx * GK + tid],       ls[tid]);
        atomicAdd(&XS[(size_t)bidx * GK + tid + 256], ls[tid + 256]);
        atomicAdd(&XS[(size_t)bidx * GK + tid + 512], ls[tid + 512]);
    }
}

// ---------------------------------------------------------------------------
// Kernel 2: transpose W [768][1024] fp32 -> Wt [1024][768] bf16 (K-contig).
// Also zeroes XS (runs before k_convX2 on the stream).
// ---------------------------------------------------------------------------
__global__ void k_transW(const float* __restrict__ W, bf16* __restrict__ Wt,
                         float* __restrict__ XS) {
    __shared__ bf16 t[32][33];
    const int k0 = blockIdx.x * 32;
    const int n0 = blockIdx.y * 32;
    const int tx = threadIdx.x, ty = threadIdx.y;
    if (XS != nullptr) {
        const int gid = (blockIdx.y * gridDim.x + blockIdx.x) * 256 + ty * 32 + tx;
        if (gid < BATCH * GK) XS[gid] = 0.f;
    }
#pragma unroll
    for (int r = 0; r < 4; ++r)
        t[ty + r * 8][tx] = (bf16)W[(size_t)(k0 + ty + r * 8) * GN + n0 + tx];
    __syncthreads();
#pragma unroll
    for (int r = 0; r < 4; ++r)
        Wt[(size_t)(n0 + ty + r * 8) * GK + k0 + tx] = t[tx][ty + r * 8];
}

// ---------------------------------------------------------------------------
// Kernel 3: out1 = squash((1/16) * xsum . W).  (round-3 validated)
// ---------------------------------------------------------------------------
__global__ __launch_bounds__(256) void k_out1(const float* __restrict__ XS,
                                              const float* __restrict__ W,
                                              float* __restrict__ O1) {
    __shared__ float xs[4][GK];      // 12 KiB
    __shared__ float red[4][4][64];  // 4 KiB [bb][kq][k]
    const int cap = blockIdx.x & 15;
    const int bg = blockIdx.x >> 4;
    const int tid = threadIdx.x;
    const int k = tid & 63, kq = tid >> 6;  // kq: kk-quarter (192 each)
#pragma unroll
    for (int bb = 0; bb < 4; ++bb) {
        const size_t b = (size_t)(bg * 4 + bb);
        xs[bb][tid]       = XS[b * GK + tid];
        xs[bb][tid + 256] = XS[b * GK + tid + 256];
        xs[bb][tid + 512] = XS[b * GK + tid + 512];
    }
    __syncthreads();
    float acc4[4] = {0.f, 0.f, 0.f, 0.f};
    const float* wp = W + (size_t)(kq * 192) * GN + cap * 64 + k;
#pragma unroll 4
    for (int kk = 0; kk < 192; ++kk) {
        const float w = wp[(size_t)kk * GN];
        const int kx = kq * 192 + kk;
        acc4[0] += xs[0][kx] * w;
        acc4[1] += xs[1][kx] * w;
        acc4[2] += xs[2][kx] * w;
        acc4[3] += xs[3][kx] * w;
    }
#pragma unroll
    for (int bb = 0; bb < 4; ++bb) red[bb][kq][k] = acc4[bb];
    __syncthreads();
    if (tid < 64) {
#pragma unroll
        for (int bb = 0; bb < 4; ++bb) {
            float s = (red[bb][0][tid] + red[bb][1][tid] +
                       red[bb][2][tid] + red[bb][3][tid]) * 0.0625f;
            float ss = s * s;
#pragma unroll
            for (int off = 32; off >= 1; off >>= 1) ss += __shfl_xor(ss, off);
            O1[((size_t)(bg * 4 + bb) * NCAP + cap) * DCAP + tid] =
                s * rsqrtf(ss + 1e-7f);
        }
    }
}

// ---------------------------------------------------------------------------
// Kernel 4: MFMA GEMM — ROUND-4: reverted to the validated 2-barrier
// single-buffer m97-style loop (82 µs structure; compiler schedules waitcnts).
// KEPT from round 3: fragment-order LDS (0 bank conflicts, measured) and the
// U-store + BL1 epilogue fusion.  No asm waitcnt, no sched_barrier (m141
// lesson: order-pinning defeats the compiler's own scheduling).
// ---------------------------------------------------------------------------
__global__ __launch_bounds__(256) void k_gemm_frag(const bf16* __restrict__ Xb,
                                                   const bf16* __restrict__ Wt,
                                                   const float* __restrict__ O1,
                                                   bf16* __restrict__ U,
                                                   float* __restrict__ BL) {
    __shared__ bf16 sA[4096];  // 8 subtiles x 512 elems (8 KiB)
    __shared__ bf16 sB[4096];

    const int tid = threadIdx.x;
    const int lane = tid & 63;
    const int wave = tid >> 6;
    const int wm = wave >> 1, wn = wave & 1;
    const int m0 = blockIdx.x * 128;
    const int n0 = blockIdx.y * 128;

    // staging source (fragment order): lane l holds row (l&15), k-part (l>>4)
    const int r16 = lane & 15, q8 = (lane >> 4) * 8;
    const bf16* gA0 = Xb + (size_t)(m0 + wave * 16 + r16) * GK + q8;
    const bf16* gA1 = Xb + (size_t)(m0 + (wave + 4) * 16 + r16) * GK + q8;
    const bf16* gB0 = Wt + (size_t)(n0 + wave * 16 + r16) * GK + q8;
    const bf16* gB1 = Wt + (size_t)(n0 + (wave + 4) * 16 + r16) * GK + q8;

    f32x4 acc[4][4] = {};

    for (int kt = 0; kt < GK / 32; ++kt) {
        __syncthreads();
        async16(gA0, sA + wave * 512);
        async16(gA1, sA + (wave + 4) * 512);
        async16(gB0, sB + wave * 512);
        async16(gB1, sB + (wave + 4) * 512);
        gA0 += 32; gA1 += 32; gB0 += 32; gB1 += 32;
        __syncthreads();

        bf16x8 af[4], bv[4];
#pragma unroll
        for (int mi = 0; mi < 4; ++mi)
            af[mi] = *(const bf16x8*)(sA + (wm * 4 + mi) * 512 + lane * 8);
#pragma unroll
        for (int ni = 0; ni < 4; ++ni)
            bv[ni] = *(const bf16x8*)(sB + (wn * 4 + ni) * 512 + lane * 8);
#pragma unroll
        for (int mi = 0; mi < 4; ++mi)
#pragma unroll
            for (int ni = 0; ni < 4; ++ni)
                acc[mi][ni] = __builtin_amdgcn_mfma_f32_16x16x32_bf16(
                    af[mi], bv[ni], acc[mi][ni], 0, 0, 0);
    }

    // --- epilogue: U store (validated mapping) ---
    const int fr = lane & 15;
    const int fq = lane >> 4;
#pragma unroll
    for (int mi = 0; mi < 4; ++mi) {
#pragma unroll
        for (int ni = 0; ni < 4; ++ni) {
#pragma unroll
            for (int r = 0; r < 4; ++r) {
                const int m = m0 + wm * 64 + mi * 16 + fq * 4 + r;
                const int n = n0 + wn * 64 + ni * 16 + fr;
                const int bb = m >> 9, j = m & 511;
                const int ci = n >> 6, k = n & 63;
                U[(((size_t)(bb * NCAP + ci)) * IN_CAPS + j) * DCAP + k] =
                    (bf16)acc[mi][ni][r];
            }
        }
    }

    // --- epilogue: BL1[b,cap,j] = <out1[b,cap,:], u[b,cap,j,:]> (validated) ---
    if (O1 != nullptr) {
        const int b = m0 >> 9;              // block rows stay within one b
        const int cap = (n0 >> 6) + wn;     // wave's 64-col strip = one capsule
        float o1v[4];
#pragma unroll
        for (int ni = 0; ni < 4; ++ni)
            o1v[ni] = O1[(size_t)b * GN + n0 + wn * 64 + ni * 16 + fr];
#pragma unroll
        for (int mi = 0; mi < 4; ++mi) {
#pragma unroll
            for (int r = 0; r < 4; ++r) {
                float p = o1v[0] * acc[mi][0][r] + o1v[1] * acc[mi][1][r] +
                          o1v[2] * acc[mi][2][r] + o1v[3] * acc[mi][3][r];
                p += __shfl_xor(p, 1);  // reduce over fr (lane bits 0..3)
                p += __shfl_xor(p, 2);
                p += __shfl_xor(p, 4);
                p += __shfl_xor(p, 8);
                if (fr == 0) {
                    const int j = (m0 & 511) + wm * 64 + mi * 16 + fq * 4 + r;
                    BL[((size_t)(b * NCAP + cap)) * IN_CAPS + j] = p;
                }
            }
        }
    }
}

// ---------------------------------------------------------------------------
// Kernel 4b: fallback GEMM (validated, inline conversion) — only if ws can't
// hold Xb.
// ---------------------------------------------------------------------------
__global__ __launch_bounds__(256) void k_gemm_inline(const float* __restrict__ X,
                                                     const bf16* __restrict__ Wt,
                                                     bf16* __restrict__ U) {
    __shared__ bf16 sA[128 * 32];
    __shared__ bf16 sB[128 * 32];
    const int tid = threadIdx.x;
    const int lane = tid & 63;
    const int wave = tid >> 6;
    const int wm = wave >> 1, wn = wave & 1;
    const int m0 = blockIdx.x * 128;
    const int n0 = blockIdx.y * 128;
    const int srow = tid >> 2;
    const int scol = (tid & 3) * 8;
    f32x4 acc[4][4] = {};
    const int fr = lane & 15;
    const int fq = lane >> 4;
    for (int kt = 0; kt < GK / 32; ++kt) {
        const int kb = kt * 32;
        bf16x8 a0, a1, b0, b1;
        {
            const float* p = X + (size_t)(m0 + srow) * GK + kb + scol;
            const f32x4 x0 = *(const f32x4*)p, x1 = *(const f32x4*)(p + 4);
            const float* q = X + (size_t)(m0 + srow + 64) * GK + kb + scol;
            const f32x4 y0 = *(const f32x4*)q, y1 = *(const f32x4*)(q + 4);
#pragma unroll
            for (int c = 0; c < 4; ++c) {
                a0[c] = (bf16)x0[c]; a0[c + 4] = (bf16)x1[c];
                a1[c] = (bf16)y0[c]; a1[c + 4] = (bf16)y1[c];
            }
        }
        b0 = *(const bf16x8*)(Wt + (size_t)(n0 + srow) * GK + kb + scol);
        b1 = *(const bf16x8*)(Wt + (size_t)(n0 + srow + 64) * GK + kb + scol);
        __syncthreads();
        *(bf16x8*)(sA + srow * 32 + scol) = a0;
        *(bf16x8*)(sA + (srow + 64) * 32 + scol) = a1;
        *(bf16x8*)(sB + srow * 32 + scol) = b0;
        *(bf16x8*)(sB + (srow + 64) * 32 + scol) = b1;
        __syncthreads();
        bf16x8 af[4], bfr[4];
#pragma unroll
        for (int mi = 0; mi < 4; ++mi)
            af[mi] = *(const bf16x8*)(sA + (wm * 64 + mi * 16 + fr) * 32 + fq * 8);
#pragma unroll
        for (int ni = 0; ni < 4; ++ni)
            bfr[ni] = *(const bf16x8*)(sB + (wn * 64 + ni * 16 + fr) * 32 + fq * 8);
#pragma unroll
        for (int mi = 0; mi < 4; ++mi)
#pragma unroll
            for (int ni = 0; ni < 4; ++ni)
                acc[mi][ni] = __builtin_amdgcn_mfma_f32_16x16x32_bf16(
                    af[mi], bfr[ni], acc[mi][ni], 0, 0, 0);
    }
#pragma unroll
    for (int mi = 0; mi < 4; ++mi) {
#pragma unroll
        for (int ni = 0; ni < 4; ++ni) {
#pragma unroll
            for (int r = 0; r < 4; ++r) {
                const int m = m0 + wm * 64 + mi * 16 + fq * 4 + r;
                const int n = n0 + wn * 64 + ni * 16 + fr;
                const int bb = m >> 9, j = m & 511;
                const int ci = n >> 6, k = n & 63;
                U[(((size_t)(bb * NCAP + ci)) * IN_CAPS + j) * DCAP + k] =
                    (bf16)acc[mi][ni][r];
            }
        }
    }
}

// ---------------------------------------------------------------------------
// Kernel 5: routing pass v3.
// ROUND-4 changes:
//  (a) phase A also stages the U slice into LDS (ds_write_b128 of the loaded
//      value, conflict-free) -> phase B reads LDS, not global (the resident
//      set, ~8 blocks/CU x 64 KiB, never fit in the 4 MiB/XCD L2).
//  (b) j-group reduce tail: 3-step __shfl_xor wave reduce + red2[4][64]
//      replaces the 32-row serial LDS reduce.
// LDS: 64K (su) + 2K (sc) + 1K (red2) + 256B = 67.3 KiB -> 2 blocks/CU,
// still BW-bound in the single global sweep (256 B/thread in flight).
// ---------------------------------------------------------------------------
__global__ __launch_bounds__(256) void k_route(const bf16* __restrict__ U,
                                               float* __restrict__ BL,
                                               float* __restrict__ OutC,
                                               int mode) {
    __shared__ bf16 su[IN_CAPS * DCAP];  // 64 KiB: the (b,cap) U-slice
    __shared__ float sc[IN_CAPS];        // 2 KiB: c[j]
    __shared__ float red2[4][64];        // 1 KiB: per-wave partials per k
    __shared__ float sout[64];           // 256 B
    const int bi = blockIdx.x;          // b*16 + cap
    const int b = bi >> 4, cap = bi & 15;
    const int tid = threadIdx.x;
    const int lane = tid & 63;
    const int wave = tid >> 6;
    const size_t ubase = (size_t)bi * IN_CAPS * DCAP;

    // --- fused softmax over the 16-capsule axis -> c[j] for own capsule ---
    if (mode == 0) {
        sc[tid] = 0.0625f;
        sc[tid + 256] = 0.0625f;
    } else {
#pragma unroll
        for (int h = 0; h < 2; ++h) {
            const int j = tid + h * 256;
            const float* p = BL + (size_t)b * NCAP * IN_CAPS + j;
            float v[16], mx = -1e30f;
#pragma unroll
            for (int i = 0; i < 16; ++i) {
                v[i] = p[(size_t)i * IN_CAPS];
                mx = fmaxf(mx, v[i]);
            }
            float s = 0.f;
#pragma unroll
            for (int i = 0; i < 16; ++i) s += __expf(v[i] - mx);
            sc[j] = __expf(v[cap] - mx) / s;
        }
    }
    __syncthreads();

    const int g = tid & 7;   // k-octet: k = g*8 .. g*8+7
    const int jr = tid >> 3; // j-row group 0..31 (= wave*8 + (lane>>3))

    // --- phase A: acc[k-octet] = sum_j c[j]*u[j][k]; stage slice into LDS ---
    float acc[8] = {};
#pragma unroll
    for (int it = 0; it < 16; ++it) {
        const int j = it * 32 + jr;
        const bf16x8 v = *(const bf16x8*)(U + ubase + (size_t)it * 2048 + tid * 8);
        if (mode != 2) *(bf16x8*)(su + it * 2048 + tid * 8) = v;
        const float cv = sc[j];
#pragma unroll
        for (int c = 0; c < 8; ++c) acc[c] += cv * (float)v[c];
    }
    // reduce over the wave's 8 j-groups (lane bits 3..5)
#pragma unroll
    for (int c = 0; c < 8; ++c) {
        acc[c] += __shfl_xor(acc[c], 8);
        acc[c] += __shfl_xor(acc[c], 16);
        acc[c] += __shfl_xor(acc[c], 32);
    }
    if ((lane >> 3) == 0) {  // lanes 0..7: lane == g
#pragma unroll
        for (int c = 0; c < 8; ++c) red2[wave][lane * 8 + c] = acc[c];
    }
    __syncthreads();

    // --- reduce 4 wave-partials per k, squash (wave 0, lane = k) ---
    if (tid < 64) {
        float s = red2[0][tid] + red2[1][tid] + red2[2][tid] + red2[3][tid];
        float ss = s * s;
#pragma unroll
        for (int off = 32; off >= 1; off >>= 1) ss += __shfl_xor(ss, off);
        const float val = s * rsqrtf(ss + 1e-7f);
        sout[tid] = val;
        if (mode == 2) OutC[(size_t)bi * DCAP + tid] = val;
    }
    if (mode == 2) return; // block-uniform
    __syncthreads();

    // --- phase B: logits bl[j] = <out, u[j]>, U-slice now in LDS ---
    const f32x4 o0 = *(const f32x4*)(sout + g * 8);
    const f32x4 o1 = *(const f32x4*)(sout + g * 8 + 4);
#pragma unroll
    for (int it = 0; it < 16; ++it) {
        const int j = it * 32 + jr;
        const bf16x8 v = *(const bf16x8*)(su + it * 2048 + tid * 8);
        float p = o0[0] * (float)v[0] + o0[1] * (float)v[1] +
                  o0[2] * (float)v[2] + o0[3] * (float)v[3] +
                  o1[0] * (float)v[4] + o1[1] * (float)v[5] +
                  o1[2] * (float)v[6] + o1[3] * (float)v[7];
        p += __shfl_xor(p, 1); // reduce over k-octets g (low 3 lane bits)
        p += __shfl_xor(p, 2);
        p += __shfl_xor(p, 4);
        if (g == 0) BL[((size_t)b * NCAP + cap) * IN_CAPS + j] = p;
    }
}

// ---------------------------------------------------------------------------
extern "C" void kernel_launch(void* const* d_in, const int* in_sizes, int n_in,
                              void* d_out, int out_size, void* d_ws, size_t ws_size,
                              hipStream_t stream) {
    const float* X = (const float*)d_in[0]; // [64][512][768] fp32
    const float* W = (const float*)d_in[1]; // [768][1024] fp32
    float* OutC = (float*)d_out;            // [64][16][64] fp32

    const size_t u_bytes = (size_t)BATCH * NCAP * IN_CAPS * DCAP * sizeof(bf16); // 64 MiB
    const size_t xb_bytes = (size_t)GM * GK * sizeof(bf16);                      // 48 MiB
    const size_t wt_bytes = (size_t)GN * GK * sizeof(bf16);                      // 1.5 MiB
    const size_t bl_bytes = (size_t)BATCH * NCAP * IN_CAPS * sizeof(float);      // 2 MiB
    const size_t xs_bytes = (size_t)BATCH * GK * sizeof(float);                  // 192 KiB
    const size_t o1_bytes = (size_t)BATCH * GN * sizeof(float);                  // 256 KiB
    char* ws = (char*)d_ws;

    const size_t need_full = u_bytes + xb_bytes + wt_bytes + bl_bytes + xs_bytes + o1_bytes;
    const size_t need_async = u_bytes + xb_bytes + wt_bytes + bl_bytes;
    const size_t need_small = u_bytes + wt_bytes + bl_bytes;

    bf16* U = (bf16*)ws;

    if (ws_size >= need_full) {
        bf16* Xb = (bf16*)(ws + u_bytes);
        bf16* Wt = (bf16*)(ws + u_bytes + xb_bytes);
        float* BL = (float*)(ws + u_bytes + xb_bytes + wt_bytes);
        float* XS = (float*)(ws + u_bytes + xb_bytes + wt_bytes + bl_bytes);
        float* O1 = (float*)(ws + u_bytes + xb_bytes + wt_bytes + bl_bytes + xs_bytes);
        // transW FIRST: zeroes XS before convX2's atomics (stream-ordered)
        k_transW<<<dim3(GK / 32, GN / 32), dim3(32, 8), 0, stream>>>(W, Wt, XS);
        k_convX2<<<GM / 32, 256, 0, stream>>>(X, Xb, XS);
        k_out1<<<256, 256, 0, stream>>>(XS, W, O1);
        k_gemm_frag<<<dim3(GM / 128, GN / 128), 256, 0, stream>>>(Xb, Wt, O1, U, BL);
        // routing iter 0 fully folded into out1 + gemm epilogue
        k_route<<<BATCH * NCAP, 256, 0, stream>>>(U, BL, OutC, 1);
        k_route<<<BATCH * NCAP, 256, 0, stream>>>(U, BL, OutC, 2);
    } else if (ws_size >= need_async) {
        bf16* Xb = (bf16*)(ws + u_bytes);
        bf16* Wt = (bf16*)(ws + u_bytes + xb_bytes);
        float* BL = (float*)(ws + u_bytes + xb_bytes + wt_bytes);
        k_transW<<<dim3(GK / 32, GN / 32), dim3(32, 8), 0, stream>>>(W, Wt, nullptr);
        k_convX2<<<GM / 32, 256, 0, stream>>>(X, Xb, nullptr);
        k_gemm_frag<<<dim3(GM / 128, GN / 128), 256, 0, stream>>>(Xb, Wt, nullptr, U, BL);
        k_route<<<BATCH * NCAP, 256, 0, stream>>>(U, BL, OutC, 0);
        k_route<<<BATCH * NCAP, 256, 0, stream>>>(U, BL, OutC, 1);
        k_route<<<BATCH * NCAP, 256, 0, stream>>>(U, BL, OutC, 2);
    } else if (ws_size >= need_small) {
        bf16* Wt = (bf16*)(ws + u_bytes);
        float* BL = (float*)(ws + u_bytes + wt_bytes);
        k_transW<<<dim3(GK / 32, GN / 32), dim3(32, 8), 0, stream>>>(W, Wt, nullptr);
        k_gemm_inline<<<dim3(GM / 128, GN / 128), 256, 0, stream>>>(X, Wt, U);
        k_route<<<BATCH * NCAP, 256, 0, stream>>>(U, BL, OutC, 0);
        k_route<<<BATCH * NCAP, 256, 0, stream>>>(U, BL, OutC, 1);
        k_route<<<BATCH * NCAP, 256, 0, stream>>>(U, BL, OutC, 2);
    }
}

// Round 5
// 295.724 us; speedup vs baseline: 1.1186x; 1.1186x over previous
//
#include <hip/hip_runtime.h>
#include <hip/hip_bf16.h>
#include <stdint.h>

// Problem constants
#define BATCH 64
#define IN_CAPS 512          // In (input capsules)
#define NCAP 16              // num_capsule
#define DCAP 64              // dim_capsule
#define GN (NCAP * DCAP)     // 1024
#define GM (BATCH * IN_CAPS) // 32768
#define GK 768               // input feature dim (K)

typedef __bf16 bf16;
typedef __attribute__((ext_vector_type(8))) __bf16 bf16x8;
typedef __attribute__((ext_vector_type(4))) float f32x4;

// async global->LDS 16B copy (wave-uniform LDS base + lane*16)
__device__ inline void async16(const bf16* g, bf16* l) {
    __builtin_amdgcn_global_load_lds(
        (__attribute__((address_space(1))) void*)g,
        (__attribute__((address_space(3))) void*)l, 16, 0, 0);
}

// ---------------------------------------------------------------------------
// Kernel 1: X (fp32) -> bf16 convert + per-b row-sum partials (for out1).
// Register accumulation (round-3 validated), single LDS merge at the end.
// ---------------------------------------------------------------------------
__global__ __launch_bounds__(256) void k_convX2(const float* __restrict__ X,
                                                bf16* __restrict__ Xb,
                                                float* __restrict__ XS) {
    __shared__ float ls[GK];
    const int tid = threadIdx.x;
    ls[tid] = 0.f; ls[tid + 256] = 0.f; ls[tid + 512] = 0.f;
    __syncthreads();
    const size_t base = (size_t)blockIdx.x * (32 * GK);
    float acc[3][8] = {};  // static indices only (g = r%3 is compile-time)
#pragma unroll
    for (int r = 0; r < 12; ++r) {
        const int off = r * 2048 + tid * 8;  // 12*2048 = 24576 = 32*768
        const f32x4 a0 = *(const f32x4*)(X + base + off);
        const f32x4 a1 = *(const f32x4*)(X + base + off + 4);
        bf16x8 o;
        o[0] = (bf16)a0[0]; o[1] = (bf16)a0[1]; o[2] = (bf16)a0[2]; o[3] = (bf16)a0[3];
        o[4] = (bf16)a1[0]; o[5] = (bf16)a1[1]; o[6] = (bf16)a1[2]; o[7] = (bf16)a1[3];
        *(bf16x8*)(Xb + base + off) = o;
        const int g = r % 3;  // compile-time within the unrolled body
        acc[g][0] += a0[0]; acc[g][1] += a0[1];
        acc[g][2] += a0[2]; acc[g][3] += a0[3];
        acc[g][4] += a1[0]; acc[g][5] += a1[1];
        acc[g][6] += a1[2]; acc[g][7] += a1[3];
    }
    if (XS != nullptr) {
        // one-time merge: 24 LDS atomics/thread, off the streaming path
#pragma unroll
        for (int g = 0; g < 3; ++g) {
            const int cg = (g == 1) ? 512 : (g == 2) ? 256 : 0;
            const int kb = (tid * 8 + cg) % GK;  // 8-group never straddles row end
#pragma unroll
            for (int j = 0; j < 8; ++j) atomicAdd(&ls[kb + j], acc[g][j]);
        }
        __syncthreads();
        const int bidx = blockIdx.x >> 4;  // 16 blocks of 32 rows per b
        atomicAdd(&XS[(size_t)bidx * GK + tid],       ls[tid]);
        atomicAdd(&XS[(size_t)bidx * GK + tid + 256], ls[tid + 256]);
        atomicAdd(&XS[(size_t)bidx * GK + tid + 512], ls[tid + 512]);
    }
}

// ---------------------------------------------------------------------------
// Kernel 2: transpose W [768][1024] fp32 -> Wt [1024][768] bf16 (K-contig).
// Also zeroes XS (runs before k_convX2 on the stream).
// ---------------------------------------------------------------------------
__global__ void k_transW(const float* __restrict__ W, bf16* __restrict__ Wt,
                         float* __restrict__ XS) {
    __shared__ bf16 t[32][33];
    const int k0 = blockIdx.x * 32;
    const int n0 = blockIdx.y * 32;
    const int tx = threadIdx.x, ty = threadIdx.y;
    if (XS != nullptr) {
        const int gid = (blockIdx.y * gridDim.x + blockIdx.x) * 256 + ty * 32 + tx;
        if (gid < BATCH * GK) XS[gid] = 0.f;
    }
#pragma unroll
    for (int r = 0; r < 4; ++r)
        t[ty + r * 8][tx] = (bf16)W[(size_t)(k0 + ty + r * 8) * GN + n0 + tx];
    __syncthreads();
#pragma unroll
    for (int r = 0; r < 4; ++r)
        Wt[(size_t)(n0 + ty + r * 8) * GK + k0 + tx] = t[tx][ty + r * 8];
}

// ---------------------------------------------------------------------------
// Kernel 3: out1 = squash((1/16) * xsum . W).  (round-3 validated)
// ---------------------------------------------------------------------------
__global__ __launch_bounds__(256) void k_out1(const float* __restrict__ XS,
                                              const float* __restrict__ W,
                                              float* __restrict__ O1) {
    __shared__ float xs[4][GK];      // 12 KiB
    __shared__ float red[4][4][64];  // 4 KiB [bb][kq][k]
    const int cap = blockIdx.x & 15;
    const int bg = blockIdx.x >> 4;
    const int tid = threadIdx.x;
    const int k = tid & 63, kq = tid >> 6;  // kq: kk-quarter (192 each)
#pragma unroll
    for (int bb = 0; bb < 4; ++bb) {
        const size_t b = (size_t)(bg * 4 + bb);
        xs[bb][tid]       = XS[b * GK + tid];
        xs[bb][tid + 256] = XS[b * GK + tid + 256];
        xs[bb][tid + 512] = XS[b * GK + tid + 512];
    }
    __syncthreads();
    float acc4[4] = {0.f, 0.f, 0.f, 0.f};
    const float* wp = W + (size_t)(kq * 192) * GN + cap * 64 + k;
#pragma unroll 4
    for (int kk = 0; kk < 192; ++kk) {
        const float w = wp[(size_t)kk * GN];
        const int kx = kq * 192 + kk;
        acc4[0] += xs[0][kx] * w;
        acc4[1] += xs[1][kx] * w;
        acc4[2] += xs[2][kx] * w;
        acc4[3] += xs[3][kx] * w;
    }
#pragma unroll
    for (int bb = 0; bb < 4; ++bb) red[bb][kq][k] = acc4[bb];
    __syncthreads();
    if (tid < 64) {
#pragma unroll
        for (int bb = 0; bb < 4; ++bb) {
            float s = (red[bb][0][tid] + red[bb][1][tid] +
                       red[bb][2][tid] + red[bb][3][tid]) * 0.0625f;
            float ss = s * s;
#pragma unroll
            for (int off = 32; off >= 1; off >>= 1) ss += __shfl_xor(ss, off);
            O1[((size_t)(bg * 4 + bb) * NCAP + cap) * DCAP + tid] =
                s * rsqrtf(ss + 1e-7f);
        }
    }
}

// ---------------------------------------------------------------------------
// Kernel 4: MFMA GEMM — ROUND-5: byte-exact restore of the round-0 validated
// 82 µs staging (address-ordered lanes: 4-lane clusters read 64 B contiguous;
// row-major LDS; original fragment reads).  The round-3/4 "fragment-order"
// staging put consecutive lanes 1536 B apart -> 4x the TA line-requests per
// staging instruction -> 122 µs.  The ~6.3M bank-conflict cycles it removed
// are only ~6 µs — bad trade.  DO NOT trade intra-wave address order for
// LDS conflict purity here.
// KEPT: U-store + BL1 epilogue fusion (validated rounds 3-4, lane-mapping
// independent of staging).
// ---------------------------------------------------------------------------
__global__ __launch_bounds__(256) void k_gemm_async(const bf16* __restrict__ Xb,
                                                    const bf16* __restrict__ Wt,
                                                    const float* __restrict__ O1,
                                                    bf16* __restrict__ U,
                                                    float* __restrict__ BL) {
    __shared__ bf16 sA[128 * 32];
    __shared__ bf16 sB[128 * 32];

    const int tid = threadIdx.x;
    const int lane = tid & 63;
    const int wave = tid >> 6;
    const int wm = wave >> 1, wn = wave & 1;
    const int m0 = blockIdx.x * 128;
    const int n0 = blockIdx.y * 128;

    const int c0 = wave * 2, c1 = wave * 2 + 1;
    const int rl = lane >> 2, cl = (lane & 3) * 8;
    const bf16* gA0 = Xb + (size_t)(m0 + c0 * 16 + rl) * GK + cl;
    const bf16* gA1 = Xb + (size_t)(m0 + c1 * 16 + rl) * GK + cl;
    const bf16* gB0 = Wt + (size_t)(n0 + c0 * 16 + rl) * GK + cl;
    const bf16* gB1 = Wt + (size_t)(n0 + c1 * 16 + rl) * GK + cl;
    bf16* lA0 = sA + c0 * 512;
    bf16* lA1 = sA + c1 * 512;
    bf16* lB0 = sB + c0 * 512;
    bf16* lB1 = sB + c1 * 512;

    f32x4 acc[4][4] = {};
    const int fr = lane & 15;
    const int fq = lane >> 4;

    for (int kt = 0; kt < GK / 32; ++kt) {
        __syncthreads();
        async16(gA0, lA0);
        async16(gA1, lA1);
        async16(gB0, lB0);
        async16(gB1, lB1);
        gA0 += 32; gA1 += 32; gB0 += 32; gB1 += 32;
        __syncthreads();

        bf16x8 af[4], bfr[4];
#pragma unroll
        for (int mi = 0; mi < 4; ++mi)
            af[mi] = *(const bf16x8*)(sA + (wm * 64 + mi * 16 + fr) * 32 + fq * 8);
#pragma unroll
        for (int ni = 0; ni < 4; ++ni)
            bfr[ni] = *(const bf16x8*)(sB + (wn * 64 + ni * 16 + fr) * 32 + fq * 8);
#pragma unroll
        for (int mi = 0; mi < 4; ++mi)
#pragma unroll
            for (int ni = 0; ni < 4; ++ni)
                acc[mi][ni] = __builtin_amdgcn_mfma_f32_16x16x32_bf16(
                    af[mi], bfr[ni], acc[mi][ni], 0, 0, 0);
    }

    // --- epilogue: U store (validated mapping) ---
#pragma unroll
    for (int mi = 0; mi < 4; ++mi) {
#pragma unroll
        for (int ni = 0; ni < 4; ++ni) {
#pragma unroll
            for (int r = 0; r < 4; ++r) {
                const int m = m0 + wm * 64 + mi * 16 + fq * 4 + r;
                const int n = n0 + wn * 64 + ni * 16 + fr;
                const int bb = m >> 9, j = m & 511;
                const int ci = n >> 6, k = n & 63;
                U[(((size_t)(bb * NCAP + ci)) * IN_CAPS + j) * DCAP + k] =
                    (bf16)acc[mi][ni][r];
            }
        }
    }

    // --- epilogue: BL1[b,cap,j] = <out1[b,cap,:], u[b,cap,j,:]> (validated) ---
    if (O1 != nullptr) {
        const int b = m0 >> 9;              // block rows stay within one b
        const int cap = (n0 >> 6) + wn;     // wave's 64-col strip = one capsule
        float o1v[4];
#pragma unroll
        for (int ni = 0; ni < 4; ++ni)
            o1v[ni] = O1[(size_t)b * GN + n0 + wn * 64 + ni * 16 + fr];
#pragma unroll
        for (int mi = 0; mi < 4; ++mi) {
#pragma unroll
            for (int r = 0; r < 4; ++r) {
                float p = o1v[0] * acc[mi][0][r] + o1v[1] * acc[mi][1][r] +
                          o1v[2] * acc[mi][2][r] + o1v[3] * acc[mi][3][r];
                p += __shfl_xor(p, 1);  // reduce over fr (lane bits 0..3)
                p += __shfl_xor(p, 2);
                p += __shfl_xor(p, 4);
                p += __shfl_xor(p, 8);
                if (fr == 0) {
                    const int j = (m0 & 511) + wm * 64 + mi * 16 + fq * 4 + r;
                    BL[((size_t)(b * NCAP + cap)) * IN_CAPS + j] = p;
                }
            }
        }
    }
}

// ---------------------------------------------------------------------------
// Kernel 4b: fallback GEMM (validated, inline conversion) — only if ws can't
// hold Xb.
// ---------------------------------------------------------------------------
__global__ __launch_bounds__(256) void k_gemm_inline(const float* __restrict__ X,
                                                     const bf16* __restrict__ Wt,
                                                     bf16* __restrict__ U) {
    __shared__ bf16 sA[128 * 32];
    __shared__ bf16 sB[128 * 32];
    const int tid = threadIdx.x;
    const int lane = tid & 63;
    const int wave = tid >> 6;
    const int wm = wave >> 1, wn = wave & 1;
    const int m0 = blockIdx.x * 128;
    const int n0 = blockIdx.y * 128;
    const int srow = tid >> 2;
    const int scol = (tid & 3) * 8;
    f32x4 acc[4][4] = {};
    const int fr = lane & 15;
    const int fq = lane >> 4;
    for (int kt = 0; kt < GK / 32; ++kt) {
        const int kb = kt * 32;
        bf16x8 a0, a1, b0, b1;
        {
            const float* p = X + (size_t)(m0 + srow) * GK + kb + scol;
            const f32x4 x0 = *(const f32x4*)p, x1 = *(const f32x4*)(p + 4);
            const float* q = X + (size_t)(m0 + srow + 64) * GK + kb + scol;
            const f32x4 y0 = *(const f32x4*)q, y1 = *(const f32x4*)(q + 4);
#pragma unroll
            for (int c = 0; c < 4; ++c) {
                a0[c] = (bf16)x0[c]; a0[c + 4] = (bf16)x1[c];
                a1[c] = (bf16)y0[c]; a1[c + 4] = (bf16)y1[c];
            }
        }
        b0 = *(const bf16x8*)(Wt + (size_t)(n0 + srow) * GK + kb + scol);
        b1 = *(const bf16x8*)(Wt + (size_t)(n0 + srow + 64) * GK + kb + scol);
        __syncthreads();
        *(bf16x8*)(sA + srow * 32 + scol) = a0;
        *(bf16x8*)(sA + (srow + 64) * 32 + scol) = a1;
        *(bf16x8*)(sB + srow * 32 + scol) = b0;
        *(bf16x8*)(sB + (srow + 64) * 32 + scol) = b1;
        __syncthreads();
        bf16x8 af[4], bfr[4];
#pragma unroll
        for (int mi = 0; mi < 4; ++mi)
            af[mi] = *(const bf16x8*)(sA + (wm * 64 + mi * 16 + fr) * 32 + fq * 8);
#pragma unroll
        for (int ni = 0; ni < 4; ++ni)
            bfr[ni] = *(const bf16x8*)(sB + (wn * 64 + ni * 16 + fr) * 32 + fq * 8);
#pragma unroll
        for (int mi = 0; mi < 4; ++mi)
#pragma unroll
            for (int ni = 0; ni < 4; ++ni)
                acc[mi][ni] = __builtin_amdgcn_mfma_f32_16x16x32_bf16(
                    af[mi], bfr[ni], acc[mi][ni], 0, 0, 0);
    }
#pragma unroll
    for (int mi = 0; mi < 4; ++mi) {
#pragma unroll
        for (int ni = 0; ni < 4; ++ni) {
#pragma unroll
            for (int r = 0; r < 4; ++r) {
                const int m = m0 + wm * 64 + mi * 16 + fq * 4 + r;
                const int n = n0 + wn * 64 + ni * 16 + fr;
                const int bb = m >> 9, j = m & 511;
                const int ci = n >> 6, k = n & 63;
                U[(((size_t)(bb * NCAP + ci)) * IN_CAPS + j) * DCAP + k] =
                    (bf16)acc[mi][ni][r];
            }
        }
    }
}

// ---------------------------------------------------------------------------
// Kernel 5: routing pass v4 — ROUND-5: round-0 structure (3.3 KiB LDS, high
// occupancy, phase B re-reads global U which is L2/L3-resident) + the
// round-4 shfl-reduce tail.  The 64 KiB LDS staging is REVERTED (halved
// occupancy, no measured gain).
// ---------------------------------------------------------------------------
__global__ __launch_bounds__(256) void k_route(const bf16* __restrict__ U,
                                               float* __restrict__ BL,
                                               float* __restrict__ OutC,
                                               int mode) {
    __shared__ float sc[IN_CAPS];  // 2 KiB: c[j]
    __shared__ float red2[4][64];  // 1 KiB: per-wave partials per k
    __shared__ float sout[64];     // 256 B
    const int bi = blockIdx.x;          // b*16 + cap
    const int b = bi >> 4, cap = bi & 15;
    const int tid = threadIdx.x;
    const int lane = tid & 63;
    const int wave = tid >> 6;
    const size_t ubase = (size_t)bi * IN_CAPS * DCAP;

    // --- fused softmax over the 16-capsule axis -> c[j] for own capsule ---
    if (mode == 0) {
        sc[tid] = 0.0625f;
        sc[tid + 256] = 0.0625f;
    } else {
#pragma unroll
        for (int h = 0; h < 2; ++h) {
            const int j = tid + h * 256;
            const float* p = BL + (size_t)b * NCAP * IN_CAPS + j;
            float v[16], mx = -1e30f;
#pragma unroll
            for (int i = 0; i < 16; ++i) {
                v[i] = p[(size_t)i * IN_CAPS];
                mx = fmaxf(mx, v[i]);
            }
            float s = 0.f;
#pragma unroll
            for (int i = 0; i < 16; ++i) s += __expf(v[i] - mx);
            sc[j] = __expf(v[cap] - mx) / s;
        }
    }
    __syncthreads();

    const int g = tid & 7;   // k-octet: k = g*8 .. g*8+7
    const int jr = tid >> 3; // j-row group 0..31 (= wave*8 + (lane>>3))

    // --- phase A: acc[k-octet] = sum_j c[j] * u[j][k], coalesced 16B/lane ---
    float acc[8] = {};
#pragma unroll
    for (int it = 0; it < 16; ++it) {
        const int j = it * 32 + jr;
        const bf16x8 v = *(const bf16x8*)(U + ubase + (size_t)it * 2048 + tid * 8);
        const float cv = sc[j];
#pragma unroll
        for (int c = 0; c < 8; ++c) acc[c] += cv * (float)v[c];
    }
    // reduce over the wave's 8 j-groups (lane bits 3..5)
#pragma unroll
    for (int c = 0; c < 8; ++c) {
        acc[c] += __shfl_xor(acc[c], 8);
        acc[c] += __shfl_xor(acc[c], 16);
        acc[c] += __shfl_xor(acc[c], 32);
    }
    if ((lane >> 3) == 0) {  // lanes 0..7: lane == g
#pragma unroll
        for (int c = 0; c < 8; ++c) red2[wave][lane * 8 + c] = acc[c];
    }
    __syncthreads();

    // --- reduce 4 wave-partials per k, squash (wave 0, lane = k) ---
    if (tid < 64) {
        float s = red2[0][tid] + red2[1][tid] + red2[2][tid] + red2[3][tid];
        float ss = s * s;
#pragma unroll
        for (int off = 32; off >= 1; off >>= 1) ss += __shfl_xor(ss, off);
        const float val = s * rsqrtf(ss + 1e-7f);
        sout[tid] = val;
        if (mode == 2) OutC[(size_t)bi * DCAP + tid] = val;
    }
    if (mode == 2) return; // block-uniform
    __syncthreads();

    // --- phase B: logits bl[j] = <out, u[j]>, re-read U (cache-hot) ---
    const f32x4 o0 = *(const f32x4*)(sout + g * 8);
    const f32x4 o1 = *(const f32x4*)(sout + g * 8 + 4);
#pragma unroll
    for (int it = 0; it < 16; ++it) {
        const int j = it * 32 + jr;
        const bf16x8 v = *(const bf16x8*)(U + ubase + (size_t)it * 2048 + tid * 8);
        float p = o0[0] * (float)v[0] + o0[1] * (float)v[1] +
                  o0[2] * (float)v[2] + o0[3] * (float)v[3] +
                  o1[0] * (float)v[4] + o1[1] * (float)v[5] +
                  o1[2] * (float)v[6] + o1[3] * (float)v[7];
        p += __shfl_xor(p, 1); // reduce over k-octets g (low 3 lane bits)
        p += __shfl_xor(p, 2);
        p += __shfl_xor(p, 4);
        if (g == 0) BL[((size_t)b * NCAP + cap) * IN_CAPS + j] = p;
    }
}

// ---------------------------------------------------------------------------
extern "C" void kernel_launch(void* const* d_in, const int* in_sizes, int n_in,
                              void* d_out, int out_size, void* d_ws, size_t ws_size,
                              hipStream_t stream) {
    const float* X = (const float*)d_in[0]; // [64][512][768] fp32
    const float* W = (const float*)d_in[1]; // [768][1024] fp32
    float* OutC = (float*)d_out;            // [64][16][64] fp32

    const size_t u_bytes = (size_t)BATCH * NCAP * IN_CAPS * DCAP * sizeof(bf16); // 64 MiB
    const size_t xb_bytes = (size_t)GM * GK * sizeof(bf16);                      // 48 MiB
    const size_t wt_bytes = (size_t)GN * GK * sizeof(bf16);                      // 1.5 MiB
    const size_t bl_bytes = (size_t)BATCH * NCAP * IN_CAPS * sizeof(float);      // 2 MiB
    const size_t xs_bytes = (size_t)BATCH * GK * sizeof(float);                  // 192 KiB
    const size_t o1_bytes = (size_t)BATCH * GN * sizeof(float);                  // 256 KiB
    char* ws = (char*)d_ws;

    const size_t need_full = u_bytes + xb_bytes + wt_bytes + bl_bytes + xs_bytes + o1_bytes;
    const size_t need_async = u_bytes + xb_bytes + wt_bytes + bl_bytes;
    const size_t need_small = u_bytes + wt_bytes + bl_bytes;

    bf16* U = (bf16*)ws;

    if (ws_size >= need_full) {
        bf16* Xb = (bf16*)(ws + u_bytes);
        bf16* Wt = (bf16*)(ws + u_bytes + xb_bytes);
        float* BL = (float*)(ws + u_bytes + xb_bytes + wt_bytes);
        float* XS = (float*)(ws + u_bytes + xb_bytes + wt_bytes + bl_bytes);
        float* O1 = (float*)(ws + u_bytes + xb_bytes + wt_bytes + bl_bytes + xs_bytes);
        // transW FIRST: zeroes XS before convX2's atomics (stream-ordered)
        k_transW<<<dim3(GK / 32, GN / 32), dim3(32, 8), 0, stream>>>(W, Wt, XS);
        k_convX2<<<GM / 32, 256, 0, stream>>>(X, Xb, XS);
        k_out1<<<256, 256, 0, stream>>>(XS, W, O1);
        k_gemm_async<<<dim3(GM / 128, GN / 128), 256, 0, stream>>>(Xb, Wt, O1, U, BL);
        // routing iter 0 fully folded into out1 + gemm epilogue
        k_route<<<BATCH * NCAP, 256, 0, stream>>>(U, BL, OutC, 1);
        k_route<<<BATCH * NCAP, 256, 0, stream>>>(U, BL, OutC, 2);
    } else if (ws_size >= need_async) {
        bf16* Xb = (bf16*)(ws + u_bytes);
        bf16* Wt = (bf16*)(ws + u_bytes + xb_bytes);
        float* BL = (float*)(ws + u_bytes + xb_bytes + wt_bytes);
        k_transW<<<dim3(GK / 32, GN / 32), dim3(32, 8), 0, stream>>>(W, Wt, nullptr);
        k_convX2<<<GM / 32, 256, 0, stream>>>(X, Xb, nullptr);
        k_gemm_async<<<dim3(GM / 128, GN / 128), 256, 0, stream>>>(Xb, Wt, nullptr, U, BL);
        k_route<<<BATCH * NCAP, 256, 0, stream>>>(U, BL, OutC, 0);
        k_route<<<BATCH * NCAP, 256, 0, stream>>>(U, BL, OutC, 1);
        k_route<<<BATCH * NCAP, 256, 0, stream>>>(U, BL, OutC, 2);
    } else if (ws_size >= need_small) {
        bf16* Wt = (bf16*)(ws + u_bytes);
        float* BL = (float*)(ws + u_bytes + wt_bytes);
        k_transW<<<dim3(GK / 32, GN / 32), dim3(32, 8), 0, stream>>>(W, Wt, nullptr);
        k_gemm_inline<<<dim3(GM / 128, GN / 128), 256, 0, stream>>>(X, Wt, U);
        k_route<<<BATCH * NCAP, 256, 0, stream>>>(U, BL, OutC, 0);
        k_route<<<BATCH * NCAP, 256, 0, stream>>>(U, BL, OutC, 1);
        k_route<<<BATCH * NCAP, 256, 0, stream>>>(U, BL, OutC, 2);
    }
}